// Round 17
// baseline (200.243 us; speedup 1.0000x reference)
//
#include <hip/hip_runtime.h>

#define H_TOKN 57
#define OUT_HW 800
#define NMASK 64
#define C_IN 768
#define C8N 96
#define L_OUT 21
#define NPIX 3249          // 57*57
#define M_TOT 6498         // 2*3249
#define YSTR 24            // y57 global channel stride
#define SCALE (57.0f/800.0f)

// fused conv
#define BM 32
#define ESTR 40            // bf16 LDS row stride
#define HSTR 97            // f32 LDS row stride

// binsum (MFMA one-hot segment sum)
#define TILE_H 25
#define TILE_W 100
#define ROWS_T 4
#define COLS_T 10
#define NTAPS 40
#define YTSTR 28
#define IPAD 264
#define ZPAD 264
#define ZROWS 32
#define NSLICE 256
#define PSTR 28

// final
#define RCSTR 28
#define MFSTR 28
#define FROWS 8

// megaB roles
#define NB_BIN 512
#define NB_FIN 200
#define RED0 200
#define NB_RED 128

static __device__ __forceinline__ unsigned short f2bf(float f) {
  unsigned u = __float_as_uint(f);
  u += 0x7FFFu + ((u >> 16) & 1u);   // RTNE
  return (unsigned short)(u >> 16);
}

using bf16x8 = __attribute__((ext_vector_type(8))) short;
using f32x4  = __attribute__((ext_vector_type(4))) float;

static __device__ __forceinline__ ushort4 cvt4(float4 v) {
  ushort4 s; s.x = f2bf(v.x); s.y = f2bf(v.y); s.z = f2bf(v.z); s.w = f2bf(v.w);
  return s;
}

// ---------- Kernel A (fused): conv1(MFMA bf16, dbuf) + relu + conv2 -> y57 ----------
// Block 0 also zeroes megaB's sync counters (stream order makes this safe on
// every call including the first).
__global__ __launch_bounds__(256) void fused_conv_kernel(
    const float* __restrict__ e, const float* __restrict__ w1,
    const float* __restrict__ b1, const float* __restrict__ w2,
    float* __restrict__ y57, unsigned* __restrict__ sync)
{
  __shared__ __align__(16) unsigned short eA[2][BM * ESTR];
  __shared__ __align__(16) unsigned short wB[2][C8N * ESTR];
  __shared__ __align__(16) float h_lds[BM * HSTR];
  __shared__ float w2_lds[L_OUT * C8N];
  __shared__ float b1_lds[C8N];

  const int tid = threadIdx.x;
  const int m0 = blockIdx.x * BM;
  const int lane = tid & 63;
  const int wv = tid >> 6;
  const int l15 = lane & 15;
  const int khi = (lane >> 4) << 3;
  const int wm = wv & 1;
  const int wn = wv >> 1;

  if (blockIdx.x == 0 && tid < 2) sync[tid] = 0u;

  for (int i = tid; i < L_OUT * C8N; i += 256) w2_lds[i] = w2[i];
  if (tid < C8N) b1_lds[tid] = b1[tid];

  const int er = tid >> 3, ec4 = (tid & 7) << 2;
  int ep = m0 + er; if (ep >= M_TOT) ep = M_TOT - 1;
  const float* eptr = e + (size_t)ep * C_IN + ec4;
  const float* wptr[3];
  int wr_[3], wc4_[3];
  #pragma unroll
  for (int q = 0; q < 3; ++q) {
    int f = tid + q * 256;
    wr_[q] = f >> 3; wc4_[q] = (f & 7) << 2;
    wptr[q] = w1 + (size_t)wr_[q] * C_IN + wc4_[q];
  }

  f32x4 acc[3];
  #pragma unroll
  for (int t = 0; t < 3; ++t) acc[t] = (f32x4){0.f, 0.f, 0.f, 0.f};

  float4 eReg = *(const float4*)(eptr);
  float4 wReg0 = *(const float4*)(wptr[0]);
  float4 wReg1 = *(const float4*)(wptr[1]);
  float4 wReg2 = *(const float4*)(wptr[2]);

  int cur = 0;
  for (int k0 = 0; k0 < C_IN; k0 += 32, cur ^= 1) {
    *(ushort4*)&eA[cur][er * ESTR + ec4] = cvt4(eReg);
    *(ushort4*)&wB[cur][wr_[0] * ESTR + wc4_[0]] = cvt4(wReg0);
    *(ushort4*)&wB[cur][wr_[1] * ESTR + wc4_[1]] = cvt4(wReg1);
    *(ushort4*)&wB[cur][wr_[2] * ESTR + wc4_[2]] = cvt4(wReg2);
    if (k0 + 32 < C_IN) {
      eReg  = *(const float4*)(eptr + k0 + 32);
      wReg0 = *(const float4*)(wptr[0] + k0 + 32);
      wReg1 = *(const float4*)(wptr[1] + k0 + 32);
      wReg2 = *(const float4*)(wptr[2] + k0 + 32);
    }
    __syncthreads();
    bf16x8 a = *(bf16x8*)&eA[cur][(wm * 16 + l15) * ESTR + khi];
    #pragma unroll
    for (int tt = 0; tt < 3; ++tt) {
      bf16x8 b = *(bf16x8*)&wB[cur][((wn * 3 + tt) * 16 + l15) * ESTR + khi];
      acc[tt] = __builtin_amdgcn_mfma_f32_16x16x32_bf16(a, b, acc[tt], 0, 0, 0);
    }
  }
  __syncthreads();
  #pragma unroll
  for (int tt = 0; tt < 3; ++tt) {
    int n = (wn * 3 + tt) * 16 + l15;
    float bv = b1_lds[n];
    #pragma unroll
    for (int r = 0; r < 4; ++r) {
      int pl = wm * 16 + ((lane >> 4) << 2) + r;
      h_lds[pl * HSTR + n] = fmaxf(acc[tt][r] + bv, 0.f);
    }
  }
  __syncthreads();
  for (int i = tid; i < BM * 24; i += 256) {
    int px = i & (BM - 1), l = i >> 5;
    float s = 0.f;
    if (l < L_OUT) {
      const float* hr = &h_lds[px * HSTR];
      const float* wr = &w2_lds[l * C8N];
      #pragma unroll 8
      for (int c = 0; c < C8N; ++c) s += hr[c] * wr[c];
    }
    int pp = m0 + px;
    if (pp < M_TOT) y57[(size_t)pp * YSTR + l] = s;
  }
}

// ---------- Kernel B (megaB): binsum + reduce + final via device spin-sync ----------
// All 512 blocks co-resident (LDS 56.9KB -> exactly 2/CU). Roles after binsum:
// bid in [200,328): reduce one bm column; bid in [0,200): final output stripe.
union SharedB {
  struct Bin {
    unsigned short It[NMASK * IPAD];
    unsigned short zT[ZROWS * ZPAD];
    float ytile[NTAPS * YTSTR];
  } bin;
  struct Red { float s_red[4][28]; } red;
  struct Fin {
    float rowC[FROWS][H_TOKN * RCSTR];
    float meanF[NMASK * MFSTR];
  } fin;
};

__global__ __launch_bounds__(256) void megaB_kernel(
    const int* __restrict__ labels, const float* __restrict__ y57,
    const float* __restrict__ b2, float* __restrict__ part,
    float* __restrict__ meanFg, float* __restrict__ out,
    unsigned* __restrict__ sync)
{
  __shared__ __align__(16) SharedB sh;
  const int tid = threadIdx.x;
  const int bid = blockIdx.x;
  const int lane = tid & 63, wv = tid >> 6;
  const int l15 = lane & 15, khi = (lane >> 4) << 3;

  // ---------------- binsum ----------------
  {
    const int b = bid >> 8;
    const int rem = bid & 255;
    const int hr0 = (rem >> 3) * TILE_H;
    const int wc0 = (rem & 7) * TILE_W;

    for (int i = tid; i < NMASK * IPAD / 2; i += 256) ((unsigned*)sh.bin.It)[i] = 0u;
    for (int i = tid; i < ZROWS * ZPAD / 2; i += 256) ((unsigned*)sh.bin.zT)[i] = 0u;

    float thb = fminf(fmaxf((hr0 + 0.5f) * SCALE - 0.5f, 0.f), 56.f);
    const int ib = min((int)thb, 55);
    float twb = fminf(fmaxf((wc0 + 0.5f) * SCALE - 0.5f, 0.f), 56.f);
    const int jb = min((int)twb, 55);

    const float* yb = y57 + (size_t)b * NPIX * YSTR;
    for (int i = tid; i < NTAPS * 6; i += 256) {
      int t = i / 6, q = (i - t * 6) * 4;
      int r = t / COLS_T, cc = t - r * COLS_T;
      int I = min(ib + r, 56), J = min(jb + cc, 56);
      *(float4*)&sh.bin.ytile[t * YTSTR + q] =
          *(const float4*)(yb + ((size_t)I * H_TOKN + J) * YSTR + q);
    }

    const bool valid = tid < 250;
    const int dh = tid / 10;
    const int dwb = (tid - dh * 10) * 10;
    const int hh = hr0 + dh;
    float th = fminf(fmaxf((hh + 0.5f) * SCALE - 0.5f, 0.f), 56.f);
    int i0 = min((int)th, 55);
    const float fh = th - (float)i0;
    const int ri = i0 - ib;
    const int* lrow = labels + ((size_t)b * OUT_HW + hh) * OUT_HW;

    f32x4 acc0 = {0.f,0.f,0.f,0.f}, acc1 = {0.f,0.f,0.f,0.f};
    int prevm = 0;
    const unsigned short one = 0x3F80;

    float u0[24], u1[24];
    int curj = -1000;
    #define LOADU(U, rj) { \
      const float* ta = &sh.bin.ytile[(ri * COLS_T + (rj)) * YTSTR]; \
      const float* tc = ta + COLS_T * YTSTR; \
      _Pragma("unroll") \
      for (int q = 0; q < 6; ++q) { \
        float4 A = *(const float4*)(ta + 4 * q); \
        float4 C = *(const float4*)(tc + 4 * q); \
        U[4*q+0] = A.x + fh * (C.x - A.x); \
        U[4*q+1] = A.y + fh * (C.y - A.y); \
        U[4*q+2] = A.z + fh * (C.z - A.z); \
        U[4*q+3] = A.w + fh * (C.w - A.w); } }

    __syncthreads();
    if (valid) sh.bin.zT[24 * ZPAD + tid] = one;

    for (int c = 0; c < 10; ++c) {
      if (valid) {
        int ww = wc0 + dwb + c;
        float tw = fminf(fmaxf((ww + 0.5f) * SCALE - 0.5f, 0.f), 56.f);
        int j0 = min((int)tw, 55);
        float fw = tw - (float)j0;
        int rj = j0 - jb;
        if (rj != curj) {
          if (rj == curj + 1) {
            #pragma unroll
            for (int ch = 0; ch < 24; ++ch) u0[ch] = u1[ch];
          } else {
            LOADU(u0, rj)
          }
          LOADU(u1, rj + 1)
          curj = rj;
        }
        int m = lrow[ww] & (NMASK - 1);
        #pragma unroll
        for (int ch = 0; ch < 24; ++ch)
          sh.bin.zT[ch * ZPAD + tid] = f2bf(u0[ch] + fw * (u1[ch] - u0[ch]));
        sh.bin.It[prevm * IPAD + tid] = 0;
        sh.bin.It[m * IPAD + tid] = one;
        prevm = m;
      }
      __syncthreads();
      #pragma unroll
      for (int ks = 0; ks < 8; ++ks) {
        bf16x8 a  = *(bf16x8*)&sh.bin.It[(wv * 16 + l15) * IPAD + ks * 32 + khi];
        bf16x8 b0 = *(bf16x8*)&sh.bin.zT[l15 * ZPAD + ks * 32 + khi];
        bf16x8 b1 = *(bf16x8*)&sh.bin.zT[(16 + l15) * ZPAD + ks * 32 + khi];
        acc0 = __builtin_amdgcn_mfma_f32_16x16x32_bf16(a, b0, acc0, 0, 0, 0);
        acc1 = __builtin_amdgcn_mfma_f32_16x16x32_bf16(a, b1, acc1, 0, 0, 0);
      }
      __syncthreads();
    }
    #undef LOADU

    float* pb = part + ((size_t)b * NSLICE + rem) * (NMASK * PSTR);
    const int g4 = (lane >> 4) << 2;
    #pragma unroll
    for (int r = 0; r < 4; ++r) {
      int m = wv * 16 + g4 + r;
      pb[m * PSTR + l15] = acc0[r];
      if (l15 <= 8) pb[m * PSTR + 16 + l15] = acc1[r];
    }
  }

  // arrival on sync[0] (release part stores)
  __threadfence();
  if (tid == 0)
    __hip_atomic_fetch_add(&sync[0], 1u, __ATOMIC_ACQ_REL, __HIP_MEMORY_SCOPE_AGENT);

  // ---------------- reduce role ----------------
  if (bid >= RED0 && bid < RED0 + NB_RED) {
    if (tid == 0) {
      while (__hip_atomic_load(&sync[0], __ATOMIC_ACQUIRE, __HIP_MEMORY_SCOPE_AGENT) < NB_BIN)
        __builtin_amdgcn_s_sleep(16);
    }
    __syncthreads();
    __threadfence();
    const int bm = bid - RED0;          // b*64 + m
    const int b = bm >> 6, m = bm & 63;
    const float* p = part + ((size_t)b * NSLICE + tid) * (NMASK * PSTR) + (size_t)m * PSTR;
    float4 v[7];
    #pragma unroll
    for (int q = 0; q < 7; ++q) v[q] = *(const float4*)(p + q * 4);
    #pragma unroll
    for (int off = 32; off > 0; off >>= 1) {
      #pragma unroll
      for (int q = 0; q < 7; ++q) {
        v[q].x += __shfl_down(v[q].x, off, 64);
        v[q].y += __shfl_down(v[q].y, off, 64);
        v[q].z += __shfl_down(v[q].z, off, 64);
        v[q].w += __shfl_down(v[q].w, off, 64);
      }
    }
    const int wid = tid >> 6;
    if (lane == 0) {
      #pragma unroll
      for (int q = 0; q < 7; ++q) *(float4*)&sh.red.s_red[wid][q * 4] = v[q];
    }
    __syncthreads();
    if (tid < 28) {
      float cnt = sh.red.s_red[0][24] + sh.red.s_red[1][24] + sh.red.s_red[2][24] + sh.red.s_red[3][24];
      float t = sh.red.s_red[0][tid] + sh.red.s_red[1][tid] + sh.red.s_red[2][tid] + sh.red.s_red[3][tid];
      float o = (tid < L_OUT) ? t / fmaxf(cnt, 1.f) + b2[tid] : 0.f;
      meanFg[(size_t)bm * MFSTR + tid] = o;
    }
    __threadfence();
    __syncthreads();
    if (tid == 0)
      __hip_atomic_fetch_add(&sync[1], 1u, __ATOMIC_ACQ_REL, __HIP_MEMORY_SCOPE_AGENT);
    return;
  }

  // ---------------- final role ----------------
  if (bid >= NB_FIN) return;
  {
    if (tid == 0) {
      while (__hip_atomic_load(&sync[1], __ATOMIC_ACQUIRE, __HIP_MEMORY_SCOPE_AGENT) < NB_RED)
        __builtin_amdgcn_s_sleep(16);
    }
    __syncthreads();
    __threadfence();
    const int b = bid / 100;
    const int hh0 = (bid - b * 100) * FROWS;
    const float* yb = y57 + (size_t)b * NPIX * YSTR;

    for (int i = tid; i < FROWS * H_TOKN * 6; i += 256) {
      int r = i / (H_TOKN * 6);
      int rest = i - r * (H_TOKN * 6);
      int rr = rest / 6, q = (rest - rr * 6) * 4;
      float th = fminf(fmaxf((hh0 + r + 0.5f) * SCALE - 0.5f, 0.f), 56.f);
      int i0 = min((int)th, 55);
      float fh = th - (float)i0;
      const float* s0 = yb + ((size_t)i0 * H_TOKN + rr) * YSTR + q;
      float4 A = *(const float4*)s0;
      float4 B = *(const float4*)(s0 + H_TOKN * YSTR);
      *(float4*)&sh.fin.rowC[r][rr * RCSTR + q] = make_float4(
          A.x + fh * (B.x - A.x), A.y + fh * (B.y - A.y),
          A.z + fh * (B.z - A.z), A.w + fh * (B.w - A.w));
    }
    {
      const float* src = meanFg + (size_t)b * NMASK * MFSTR;
      for (int i = tid; i < NMASK * MFSTR / 4; i += 256)
        *(float4*)&sh.fin.meanF[i * 4] = *(const float4*)(src + i * 4);
    }
    __syncthreads();

    for (int g = tid; g < FROWS * 200; g += 256) {
      const int row = g / 200;
      const int gg = g - row * 200;
      const int w0 = gg * 4;
      const int hh = hh0 + row;
      const int* lrow = labels + ((size_t)b * OUT_HW + hh) * OUT_HW;
      int4 la = *(const int4*)(lrow + w0);
      float* ob = out + (size_t)b * L_OUT * OUT_HW * OUT_HW + (size_t)hh * OUT_HW + w0;
      const float* rc = sh.fin.rowC[row];

      float fwv[4]; const float* c0p[4]; const float* mfp[4];
      {
        int lam[4] = {la.x & 63, la.y & 63, la.z & 63, la.w & 63};
        #pragma unroll
        for (int k = 0; k < 4; ++k) {
          float tw = fminf(fmaxf((w0 + k + 0.5f) * SCALE - 0.5f, 0.f), 56.f);
          int j0 = min((int)tw, 55);
          fwv[k] = tw - (float)j0;
          c0p[k] = &rc[j0 * RCSTR];
          mfp[k] = &sh.fin.meanF[lam[k] * MFSTR];
        }
      }
      #pragma unroll
      for (int q = 0; q < 6; ++q) {
        float4 V[4];
        #pragma unroll
        for (int k = 0; k < 4; ++k) {
          float4 A  = *(const float4*)(c0p[k] + 4 * q);
          float4 Bv = *(const float4*)(c0p[k] + RCSTR + 4 * q);
          float4 Mv = *(const float4*)(mfp[k] + 4 * q);
          V[k].x = A.x + fwv[k] * (Bv.x - A.x) + Mv.x;
          V[k].y = A.y + fwv[k] * (Bv.y - A.y) + Mv.y;
          V[k].z = A.z + fwv[k] * (Bv.z - A.z) + Mv.z;
          V[k].w = A.w + fwv[k] * (Bv.w - A.w) + Mv.w;
        }
        const int l = 4 * q;
        *(float4*)(ob + (size_t)l * 640000) = make_float4(V[0].x, V[1].x, V[2].x, V[3].x);
        if (l + 1 < L_OUT)
          *(float4*)(ob + (size_t)(l+1) * 640000) = make_float4(V[0].y, V[1].y, V[2].y, V[3].y);
        if (l + 2 < L_OUT)
          *(float4*)(ob + (size_t)(l+2) * 640000) = make_float4(V[0].z, V[1].z, V[2].z, V[3].z);
        if (l + 3 < L_OUT)
          *(float4*)(ob + (size_t)(l+3) * 640000) = make_float4(V[0].w, V[1].w, V[2].w, V[3].w);
      }
    }
  }
}

extern "C" void kernel_launch(void* const* d_in, const int* in_sizes, int n_in,
                              void* d_out, int out_size, void* d_ws, size_t ws_size,
                              hipStream_t stream)
{
  const float* e   = (const float*)d_in[0];
  const int*   lab = (const int*)d_in[1];
  const float* w1  = (const float*)d_in[2];
  const float* b1  = (const float*)d_in[3];
  const float* w2  = (const float*)d_in[4];
  const float* b2  = (const float*)d_in[5];
  float* out = (float*)d_out;
  float* ws  = (float*)d_ws;

  float* y57_ws = ws;                                       // 6498*24 f32
  float* part   = y57_ws + (size_t)M_TOT * YSTR;            // 2*256*64*28 f32
  float* meanFg = part + (size_t)2 * NSLICE * NMASK * PSTR; // 2*64*28 f32
  unsigned* sync = (unsigned*)(meanFg + 2 * NMASK * MFSTR); // 2 u32

  fused_conv_kernel<<<dim3((M_TOT + BM - 1) / BM), 256, 0, stream>>>(
      e, w1, b1, w2, y57_ws, sync);
  megaB_kernel<<<dim3(NB_BIN), 256, 0, stream>>>(
      lab, y57_ws, b2, part, meanFg, out, sync);
}

// Round 18
// 138.326 us; speedup vs baseline: 1.4476x; 1.4476x over previous
//
#include <hip/hip_runtime.h>

#define H_TOKN 57
#define OUT_HW 800
#define NMASK 64
#define C_IN 768
#define C8N 96
#define L_OUT 21
#define NPIX 3249          // 57*57
#define M_TOT 6498         // 2*3249
#define YSTR 24            // y57 global channel stride
#define SCALE (57.0f/800.0f)

// fused conv
#define BM 32
#define ESTR 40            // bf16 LDS row stride
#define HSTR 97            // f32 LDS row stride

// binsum (MFMA one-hot segment sum)
#define TILE_H 25
#define TILE_W 100
#define ROWS_T 4
#define COLS_T 10
#define NTAPS 40
#define YTSTR 28
#define IPAD 264
#define ZPAD 264
#define ZROWS 32
#define NSLICE 256
#define PSTR 28
#define PROW (NMASK * PSTR)   // 1792 floats per slice

// final
#define RCSTR 28
#define MFSTR 28
#define FROWS 8

static __device__ __forceinline__ unsigned short f2bf(float f) {
  unsigned u = __float_as_uint(f);
  u += 0x7FFFu + ((u >> 16) & 1u);   // RTNE
  return (unsigned short)(u >> 16);
}

using bf16x8 = __attribute__((ext_vector_type(8))) short;
using f32x4  = __attribute__((ext_vector_type(4))) float;

static __device__ __forceinline__ ushort4 cvt4(float4 v) {
  ushort4 s; s.x = f2bf(v.x); s.y = f2bf(v.y); s.z = f2bf(v.z); s.w = f2bf(v.w);
  return s;
}

// ---------- Kernel A (fused): conv1(MFMA bf16, dbuf) + relu + conv2 -> y57 ----------
__global__ __launch_bounds__(256) void fused_conv_kernel(
    const float* __restrict__ e, const float* __restrict__ w1,
    const float* __restrict__ b1, const float* __restrict__ w2,
    float* __restrict__ y57)
{
  __shared__ __align__(16) unsigned short eA[2][BM * ESTR];
  __shared__ __align__(16) unsigned short wB[2][C8N * ESTR];
  __shared__ __align__(16) float h_lds[BM * HSTR];
  __shared__ float w2_lds[L_OUT * C8N];
  __shared__ float b1_lds[C8N];

  const int tid = threadIdx.x;
  const int m0 = blockIdx.x * BM;
  const int lane = tid & 63;
  const int wv = tid >> 6;
  const int l15 = lane & 15;
  const int khi = (lane >> 4) << 3;
  const int wm = wv & 1;
  const int wn = wv >> 1;

  for (int i = tid; i < L_OUT * C8N; i += 256) w2_lds[i] = w2[i];
  if (tid < C8N) b1_lds[tid] = b1[tid];

  const int er = tid >> 3, ec4 = (tid & 7) << 2;
  int ep = m0 + er; if (ep >= M_TOT) ep = M_TOT - 1;
  const float* eptr = e + (size_t)ep * C_IN + ec4;
  const float* wptr[3];
  int wr_[3], wc4_[3];
  #pragma unroll
  for (int q = 0; q < 3; ++q) {
    int f = tid + q * 256;
    wr_[q] = f >> 3; wc4_[q] = (f & 7) << 2;
    wptr[q] = w1 + (size_t)wr_[q] * C_IN + wc4_[q];
  }

  f32x4 acc[3];
  #pragma unroll
  for (int t = 0; t < 3; ++t) acc[t] = (f32x4){0.f, 0.f, 0.f, 0.f};

  float4 eReg = *(const float4*)(eptr);
  float4 wReg0 = *(const float4*)(wptr[0]);
  float4 wReg1 = *(const float4*)(wptr[1]);
  float4 wReg2 = *(const float4*)(wptr[2]);

  int cur = 0;
  for (int k0 = 0; k0 < C_IN; k0 += 32, cur ^= 1) {
    *(ushort4*)&eA[cur][er * ESTR + ec4] = cvt4(eReg);
    *(ushort4*)&wB[cur][wr_[0] * ESTR + wc4_[0]] = cvt4(wReg0);
    *(ushort4*)&wB[cur][wr_[1] * ESTR + wc4_[1]] = cvt4(wReg1);
    *(ushort4*)&wB[cur][wr_[2] * ESTR + wc4_[2]] = cvt4(wReg2);
    if (k0 + 32 < C_IN) {
      eReg  = *(const float4*)(eptr + k0 + 32);
      wReg0 = *(const float4*)(wptr[0] + k0 + 32);
      wReg1 = *(const float4*)(wptr[1] + k0 + 32);
      wReg2 = *(const float4*)(wptr[2] + k0 + 32);
    }
    __syncthreads();
    bf16x8 a = *(bf16x8*)&eA[cur][(wm * 16 + l15) * ESTR + khi];
    #pragma unroll
    for (int tt = 0; tt < 3; ++tt) {
      bf16x8 b = *(bf16x8*)&wB[cur][((wn * 3 + tt) * 16 + l15) * ESTR + khi];
      acc[tt] = __builtin_amdgcn_mfma_f32_16x16x32_bf16(a, b, acc[tt], 0, 0, 0);
    }
  }
  __syncthreads();
  #pragma unroll
  for (int tt = 0; tt < 3; ++tt) {
    int n = (wn * 3 + tt) * 16 + l15;
    float bv = b1_lds[n];
    #pragma unroll
    for (int r = 0; r < 4; ++r) {
      int pl = wm * 16 + ((lane >> 4) << 2) + r;
      h_lds[pl * HSTR + n] = fmaxf(acc[tt][r] + bv, 0.f);
    }
  }
  __syncthreads();
  for (int i = tid; i < BM * 24; i += 256) {
    int px = i & (BM - 1), l = i >> 5;
    float s = 0.f;
    if (l < L_OUT) {
      const float* hr = &h_lds[px * HSTR];
      const float* wr = &w2_lds[l * C8N];
      #pragma unroll 8
      for (int c = 0; c < C8N; ++c) s += hr[c] * wr[c];
    }
    int pp = m0 + px;
    if (pp < M_TOT) y57[(size_t)pp * YSTR + l] = s;
  }
}

// ---------- Kernel B: MFMA one-hot segment sum, register tap-caching ----------
__global__ __launch_bounds__(256) void binsum_kernel(
    const int* __restrict__ labels, const float* __restrict__ y57,
    float* __restrict__ part)
{
  __shared__ __align__(16) unsigned short It[NMASK * IPAD];
  __shared__ __align__(16) unsigned short zT[ZROWS * ZPAD];
  __shared__ __align__(16) float ytile[NTAPS * YTSTR];
  const int tid = threadIdx.x;
  const int lane = tid & 63, wv = tid >> 6;
  const int l15 = lane & 15, khi = (lane >> 4) << 3;
  const int wc0 = blockIdx.x * TILE_W;
  const int hr0 = blockIdx.y * TILE_H;
  const int b = blockIdx.z;

  for (int i = tid; i < NMASK * IPAD / 2; i += 256) ((unsigned*)It)[i] = 0u;
  for (int i = tid; i < ZROWS * ZPAD / 2; i += 256) ((unsigned*)zT)[i] = 0u;

  float thb = fminf(fmaxf((hr0 + 0.5f) * SCALE - 0.5f, 0.f), 56.f);
  const int ib = min((int)thb, 55);
  float twb = fminf(fmaxf((wc0 + 0.5f) * SCALE - 0.5f, 0.f), 56.f);
  const int jb = min((int)twb, 55);

  const float* yb = y57 + (size_t)b * NPIX * YSTR;
  for (int i = tid; i < NTAPS * 6; i += 256) {
    int t = i / 6, q = (i - t * 6) * 4;
    int r = t / COLS_T, cc = t - r * COLS_T;
    int I = min(ib + r, 56), J = min(jb + cc, 56);
    *(float4*)&ytile[t * YTSTR + q] =
        *(const float4*)(yb + ((size_t)I * H_TOKN + J) * YSTR + q);
  }

  const bool valid = tid < 250;
  const int dh = tid / 10;
  const int dwb = (tid - dh * 10) * 10;
  const int hh = hr0 + dh;
  float th = fminf(fmaxf((hh + 0.5f) * SCALE - 0.5f, 0.f), 56.f);
  int i0 = min((int)th, 55);
  const float fh = th - (float)i0;
  const int ri = i0 - ib;
  const int* lrow = labels + ((size_t)b * OUT_HW + hh) * OUT_HW;

  f32x4 acc0 = {0.f,0.f,0.f,0.f}, acc1 = {0.f,0.f,0.f,0.f};
  int prevm = 0;
  const unsigned short one = 0x3F80;

  float u0[24], u1[24];
  int curj = -1000;
  #define LOADU(U, rj) { \
    const float* ta = &ytile[(ri * COLS_T + (rj)) * YTSTR]; \
    const float* tc = ta + COLS_T * YTSTR; \
    _Pragma("unroll") \
    for (int q = 0; q < 6; ++q) { \
      float4 A = *(const float4*)(ta + 4 * q); \
      float4 C = *(const float4*)(tc + 4 * q); \
      U[4*q+0] = A.x + fh * (C.x - A.x); \
      U[4*q+1] = A.y + fh * (C.y - A.y); \
      U[4*q+2] = A.z + fh * (C.z - A.z); \
      U[4*q+3] = A.w + fh * (C.w - A.w); } }

  __syncthreads();
  if (valid) zT[24 * ZPAD + tid] = one;

  for (int c = 0; c < 10; ++c) {
    if (valid) {
      int ww = wc0 + dwb + c;
      float tw = fminf(fmaxf((ww + 0.5f) * SCALE - 0.5f, 0.f), 56.f);
      int j0 = min((int)tw, 55);
      float fw = tw - (float)j0;
      int rj = j0 - jb;
      if (rj != curj) {
        if (rj == curj + 1) {
          #pragma unroll
          for (int ch = 0; ch < 24; ++ch) u0[ch] = u1[ch];
        } else {
          LOADU(u0, rj)
        }
        LOADU(u1, rj + 1)
        curj = rj;
      }
      int m = lrow[ww] & (NMASK - 1);
      #pragma unroll
      for (int ch = 0; ch < 24; ++ch)
        zT[ch * ZPAD + tid] = f2bf(u0[ch] + fw * (u1[ch] - u0[ch]));
      It[prevm * IPAD + tid] = 0;
      It[m * IPAD + tid] = one;
      prevm = m;
    }
    __syncthreads();
    #pragma unroll
    for (int ks = 0; ks < 8; ++ks) {
      bf16x8 a  = *(bf16x8*)&It[(wv * 16 + l15) * IPAD + ks * 32 + khi];
      bf16x8 b0 = *(bf16x8*)&zT[l15 * ZPAD + ks * 32 + khi];
      bf16x8 b1 = *(bf16x8*)&zT[(16 + l15) * ZPAD + ks * 32 + khi];
      acc0 = __builtin_amdgcn_mfma_f32_16x16x32_bf16(a, b0, acc0, 0, 0, 0);
      acc1 = __builtin_amdgcn_mfma_f32_16x16x32_bf16(a, b1, acc1, 0, 0, 0);
    }
    __syncthreads();
  }
  #undef LOADU

  float* pb = part + ((size_t)b * NSLICE +
                      (size_t)(blockIdx.y * gridDim.x + blockIdx.x)) * PROW;
  const int g4 = (lane >> 4) << 2;
  #pragma unroll
  for (int r = 0; r < 4; ++r) {
    int m = wv * 16 + g4 + r;
    pb[m * PSTR + l15] = acc0[r];
    if (l15 <= 8) pb[m * PSTR + 16 + l15] = acc1[r];
  }
}

// ---------- Kernel C (final+reduce): per-block batch reduce, then output ----------
// Each block reduces its batch's part (256 slices x 1792 f32, L2-resident) via
// float4 accumulation, converts sums->means IN-PLACE in LDS (cnt slot l=24 is
// never overwritten), then does the usual lerp+mean pixel loop.
__global__ __launch_bounds__(256) void final_kernel(
    const float* __restrict__ y57, const int* __restrict__ labels,
    const float* __restrict__ part, const float* __restrict__ b2,
    float* __restrict__ out)
{
  __shared__ __align__(16) float rowC[FROWS][H_TOKN * RCSTR];
  __shared__ __align__(16) float meanF[PROW];   // 1792: sums then means in-place
  const int tid = threadIdx.x;
  const int hh0 = blockIdx.y * FROWS;
  const int b = blockIdx.z;
  const float* yb = y57 + (size_t)b * NPIX * YSTR;

  // ---- in-block reduction of part[b] : 448 float4 columns over 256 slices ----
  {
    const float* pb = part + (size_t)b * NSLICE * PROW;
    f32x4 a0 = {0.f,0.f,0.f,0.f}, a1 = {0.f,0.f,0.f,0.f};
    const int f0 = tid;          // float4 index 0..255
    const int f1 = tid + 256;    // 256..511 (valid when <448)
    for (int s = 0; s < NSLICE; ++s) {
      const f32x4* row = (const f32x4*)(pb + (size_t)s * PROW);
      a0 += row[f0];
      if (f1 < PROW / 4) a1 += row[f1];
    }
    *(f32x4*)&meanF[f0 * 4] = a0;
    if (f1 < PROW / 4) *(f32x4*)&meanF[f1 * 4] = a1;
  }
  // rowC staging (overlaps reduction latency via scheduler)
  for (int i = tid; i < FROWS * H_TOKN * 6; i += 256) {
    int r = i / (H_TOKN * 6);
    int rest = i - r * (H_TOKN * 6);
    int rr = rest / 6, q = (rest - rr * 6) * 4;
    float th = fminf(fmaxf((hh0 + r + 0.5f) * SCALE - 0.5f, 0.f), 56.f);
    int i0 = min((int)th, 55);
    float fh = th - (float)i0;
    const float* s0 = yb + ((size_t)i0 * H_TOKN + rr) * YSTR + q;
    float4 A = *(const float4*)s0;
    float4 B = *(const float4*)(s0 + H_TOKN * YSTR);
    *(float4*)&rowC[r][rr * RCSTR + q] = make_float4(
        A.x + fh * (B.x - A.x), A.y + fh * (B.y - A.y),
        A.z + fh * (B.z - A.z), A.w + fh * (B.w - A.w));
  }
  __syncthreads();
  // sums -> means in-place (l=24 cnt slot read-only, never written)
  for (int i = tid; i < PROW; i += 256) {
    int m = i / MFSTR, l = i - m * MFSTR;
    if (l < L_OUT) {
      float cnt = meanF[m * MFSTR + 24];
      meanF[i] = meanF[i] / fmaxf(cnt, 1.f) + b2[l];
    }
  }
  __syncthreads();

  for (int g = tid; g < FROWS * 200; g += 256) {
    const int row = g / 200;
    const int gg = g - row * 200;
    const int w0 = gg * 4;
    const int hh = hh0 + row;
    const int* lrow = labels + ((size_t)b * OUT_HW + hh) * OUT_HW;
    int4 la = *(const int4*)(lrow + w0);
    float* ob = out + (size_t)b * L_OUT * OUT_HW * OUT_HW + (size_t)hh * OUT_HW + w0;
    const float* rc = rowC[row];

    float fwv[4]; const float* c0p[4]; const float* mfp[4];
    {
      int lam[4] = {la.x & 63, la.y & 63, la.z & 63, la.w & 63};
      #pragma unroll
      for (int k = 0; k < 4; ++k) {
        float tw = fminf(fmaxf((w0 + k + 0.5f) * SCALE - 0.5f, 0.f), 56.f);
        int j0 = min((int)tw, 55);
        fwv[k] = tw - (float)j0;
        c0p[k] = &rc[j0 * RCSTR];
        mfp[k] = &meanF[lam[k] * MFSTR];
      }
    }
    #pragma unroll
    for (int q = 0; q < 6; ++q) {
      float4 V[4];
      #pragma unroll
      for (int k = 0; k < 4; ++k) {
        float4 A  = *(const float4*)(c0p[k] + 4 * q);
        float4 Bv = *(const float4*)(c0p[k] + RCSTR + 4 * q);
        float4 Mv = *(const float4*)(mfp[k] + 4 * q);
        V[k].x = A.x + fwv[k] * (Bv.x - A.x) + Mv.x;
        V[k].y = A.y + fwv[k] * (Bv.y - A.y) + Mv.y;
        V[k].z = A.z + fwv[k] * (Bv.z - A.z) + Mv.z;
        V[k].w = A.w + fwv[k] * (Bv.w - A.w) + Mv.w;
      }
      const int l = 4 * q;
      *(float4*)(ob + (size_t)l * 640000) = make_float4(V[0].x, V[1].x, V[2].x, V[3].x);
      if (l + 1 < L_OUT)
        *(float4*)(ob + (size_t)(l+1) * 640000) = make_float4(V[0].y, V[1].y, V[2].y, V[3].y);
      if (l + 2 < L_OUT)
        *(float4*)(ob + (size_t)(l+2) * 640000) = make_float4(V[0].z, V[1].z, V[2].z, V[3].z);
      if (l + 3 < L_OUT)
        *(float4*)(ob + (size_t)(l+3) * 640000) = make_float4(V[0].w, V[1].w, V[2].w, V[3].w);
    }
  }
}

extern "C" void kernel_launch(void* const* d_in, const int* in_sizes, int n_in,
                              void* d_out, int out_size, void* d_ws, size_t ws_size,
                              hipStream_t stream)
{
  const float* e   = (const float*)d_in[0];
  const int*   lab = (const int*)d_in[1];
  const float* w1  = (const float*)d_in[2];
  const float* b1  = (const float*)d_in[3];
  const float* w2  = (const float*)d_in[4];
  const float* b2  = (const float*)d_in[5];
  float* out = (float*)d_out;
  float* ws  = (float*)d_ws;

  float* y57_ws = ws;                                     // 6498*24 f32
  float* part   = y57_ws + (size_t)M_TOT * YSTR;          // 2*256*1792 f32

  fused_conv_kernel<<<dim3((M_TOT + BM - 1) / BM), 256, 0, stream>>>(
      e, w1, b1, w2, y57_ws);
  binsum_kernel<<<dim3(OUT_HW / TILE_W, OUT_HW / TILE_H, 2), 256, 0, stream>>>(
      lab, y57_ws, part);
  final_kernel<<<dim3(1, OUT_HW / FROWS, 2), 256, 0, stream>>>(
      y57_ws, lab, part, b2, out);
}

// Round 19
// 65.572 us; speedup vs baseline: 3.0538x; 2.1095x over previous
//
#include <hip/hip_runtime.h>

#define H_TOKN 57
#define OUT_HW 800
#define NMASK 64
#define C_IN 768
#define C8N 96
#define L_OUT 21
#define NPIX 3249          // 57*57
#define M_TOT 6498         // 2*3249
#define YSTR 24            // y57 global channel stride
#define SCALE (57.0f/800.0f)

// fused conv: BM=16, 384 threads (6 waves, 1 n-tile each) -> 407 blocks
#define BM 16
#define NTHR 384
#define ESTR 40            // bf16 LDS row stride
#define HSTR 97            // f32 LDS row stride

// binsum (MFMA one-hot segment sum)
#define TILE_H 25
#define TILE_W 100
#define ROWS_T 4
#define COLS_T 10
#define NTAPS 40
#define YTSTR 28
#define IPAD 264
#define ZPAD 264
#define ZROWS 32
#define NSLICE 256
#define PSTR 28

// final
#define RCSTR 28
#define MFSTR 28
#define FROWS 8

static __device__ __forceinline__ unsigned short f2bf(float f) {
  unsigned u = __float_as_uint(f);
  u += 0x7FFFu + ((u >> 16) & 1u);   // RTNE
  return (unsigned short)(u >> 16);
}

using bf16x8 = __attribute__((ext_vector_type(8))) short;
using f32x4  = __attribute__((ext_vector_type(4))) float;

static __device__ __forceinline__ ushort4 cvt4(float4 v) {
  ushort4 s; s.x = f2bf(v.x); s.y = f2bf(v.y); s.z = f2bf(v.z); s.w = f2bf(v.w);
  return s;
}

// ---------- Kernel A (fused): conv1(MFMA bf16, dbuf) + relu + conv2 -> y57 ----------
// 407 blocks (1.6/CU), 6 waves: wave wv owns n-tile wv (16 cols). One barrier
// per K-iter (write-after-read separated by >=1 barrier via double buffer).
__global__ __launch_bounds__(NTHR) void fused_conv_kernel(
    const float* __restrict__ e, const float* __restrict__ w1,
    const float* __restrict__ b1, const float* __restrict__ w2,
    float* __restrict__ y57)
{
  __shared__ __align__(16) unsigned short eA[2][BM * ESTR];   // 2x1.28KB
  __shared__ __align__(16) unsigned short wB[2][C8N * ESTR];  // 2x7.7KB
  __shared__ __align__(16) float h_lds[BM * HSTR];            // 6.2KB
  __shared__ float w2_lds[L_OUT * C8N];
  __shared__ float b1_lds[C8N];

  const int tid = threadIdx.x;
  const int m0 = blockIdx.x * BM;
  const int lane = tid & 63;
  const int wv = tid >> 6;            // 0..5 = n-tile
  const int l15 = lane & 15;
  const int khi = (lane >> 4) << 3;   // k-offset 0,8,16,24

  for (int i = tid; i < L_OUT * C8N; i += NTHR) w2_lds[i] = w2[i];
  if (tid < C8N) b1_lds[tid] = b1[tid];

  // staging: e tile (16 rows x 8 float4) by threads 0..127; w1 (96 x 8 f4) 2/thread
  const bool estage = tid < 128;
  const int er = tid >> 3, ec4 = (tid & 7) << 2;
  int ep = m0 + er; if (ep >= M_TOT) ep = M_TOT - 1;
  const float* eptr = e + (size_t)ep * C_IN + ec4;
  const int f0 = tid, f1 = tid + NTHR;
  const int wr0 = f0 >> 3, wc40 = (f0 & 7) << 2;
  const int wr1 = f1 >> 3, wc41 = (f1 & 7) << 2;
  const float* wptr0 = w1 + (size_t)wr0 * C_IN + wc40;
  const float* wptr1 = w1 + (size_t)wr1 * C_IN + wc41;

  f32x4 acc = {0.f, 0.f, 0.f, 0.f};

  float4 eReg = estage ? *(const float4*)(eptr) : make_float4(0,0,0,0);
  float4 wReg0 = *(const float4*)(wptr0);
  float4 wReg1 = *(const float4*)(wptr1);

  int cur = 0;
  for (int k0 = 0; k0 < C_IN; k0 += 32, cur ^= 1) {
    if (estage) *(ushort4*)&eA[cur][er * ESTR + ec4] = cvt4(eReg);
    *(ushort4*)&wB[cur][wr0 * ESTR + wc40] = cvt4(wReg0);
    *(ushort4*)&wB[cur][wr1 * ESTR + wc41] = cvt4(wReg1);
    if (k0 + 32 < C_IN) {
      if (estage) eReg = *(const float4*)(eptr + k0 + 32);
      wReg0 = *(const float4*)(wptr0 + k0 + 32);
      wReg1 = *(const float4*)(wptr1 + k0 + 32);
    }
    __syncthreads();
    bf16x8 a = *(bf16x8*)&eA[cur][l15 * ESTR + khi];
    bf16x8 b = *(bf16x8*)&wB[cur][(wv * 16 + l15) * ESTR + khi];
    acc = __builtin_amdgcn_mfma_f32_16x16x32_bf16(a, b, acc, 0, 0, 0);
  }
  __syncthreads();
  // h = relu(acc + b1).  D: col=lane&15 (=n within tile), row=4*(lane>>4)+reg (=px)
  {
    int n = wv * 16 + l15;
    float bv = b1_lds[n];
    #pragma unroll
    for (int r = 0; r < 4; ++r) {
      int pl = ((lane >> 4) << 2) + r;
      h_lds[pl * HSTR + n] = fmaxf(acc[r] + bv, 0.f);
    }
  }
  __syncthreads();
  // conv2: exactly one output per thread (384 = 16 px x 24 l)
  {
    int px = tid & (BM - 1), l = tid >> 4;
    float s = 0.f;
    if (l < L_OUT) {
      const float* hr = &h_lds[px * HSTR];
      const float* wr = &w2_lds[l * C8N];
      #pragma unroll 8
      for (int c = 0; c < C8N; ++c) s += hr[c] * wr[c];
    }
    int pp = m0 + px;
    if (pp < M_TOT) y57[(size_t)pp * YSTR + l] = s;
  }
}

// ---------- Kernel B: MFMA one-hot segment sum, register tap-caching ----------
__global__ __launch_bounds__(256) void binsum_kernel(
    const int* __restrict__ labels, const float* __restrict__ y57,
    float* __restrict__ part)
{
  __shared__ __align__(16) unsigned short It[NMASK * IPAD];
  __shared__ __align__(16) unsigned short zT[ZROWS * ZPAD];
  __shared__ __align__(16) float ytile[NTAPS * YTSTR];
  const int tid = threadIdx.x;
  const int lane = tid & 63, wv = tid >> 6;
  const int l15 = lane & 15, khi = (lane >> 4) << 3;
  const int wc0 = blockIdx.x * TILE_W;
  const int hr0 = blockIdx.y * TILE_H;
  const int b = blockIdx.z;

  for (int i = tid; i < NMASK * IPAD / 2; i += 256) ((unsigned*)It)[i] = 0u;
  for (int i = tid; i < ZROWS * ZPAD / 2; i += 256) ((unsigned*)zT)[i] = 0u;

  float thb = fminf(fmaxf((hr0 + 0.5f) * SCALE - 0.5f, 0.f), 56.f);
  const int ib = min((int)thb, 55);
  float twb = fminf(fmaxf((wc0 + 0.5f) * SCALE - 0.5f, 0.f), 56.f);
  const int jb = min((int)twb, 55);

  const float* yb = y57 + (size_t)b * NPIX * YSTR;
  for (int i = tid; i < NTAPS * 6; i += 256) {
    int t = i / 6, q = (i - t * 6) * 4;
    int r = t / COLS_T, cc = t - r * COLS_T;
    int I = min(ib + r, 56), J = min(jb + cc, 56);
    *(float4*)&ytile[t * YTSTR + q] =
        *(const float4*)(yb + ((size_t)I * H_TOKN + J) * YSTR + q);
  }

  const bool valid = tid < 250;
  const int dh = tid / 10;
  const int dwb = (tid - dh * 10) * 10;
  const int hh = hr0 + dh;
  float th = fminf(fmaxf((hh + 0.5f) * SCALE - 0.5f, 0.f), 56.f);
  int i0 = min((int)th, 55);
  const float fh = th - (float)i0;
  const int ri = i0 - ib;
  const int* lrow = labels + ((size_t)b * OUT_HW + hh) * OUT_HW;

  f32x4 acc0 = {0.f,0.f,0.f,0.f}, acc1 = {0.f,0.f,0.f,0.f};
  int prevm = 0;
  const unsigned short one = 0x3F80;

  float u0[24], u1[24];
  int curj = -1000;
  #define LOADU(U, rj) { \
    const float* ta = &ytile[(ri * COLS_T + (rj)) * YTSTR]; \
    const float* tc = ta + COLS_T * YTSTR; \
    _Pragma("unroll") \
    for (int q = 0; q < 6; ++q) { \
      float4 A = *(const float4*)(ta + 4 * q); \
      float4 C = *(const float4*)(tc + 4 * q); \
      U[4*q+0] = A.x + fh * (C.x - A.x); \
      U[4*q+1] = A.y + fh * (C.y - A.y); \
      U[4*q+2] = A.z + fh * (C.z - A.z); \
      U[4*q+3] = A.w + fh * (C.w - A.w); } }

  __syncthreads();
  if (valid) zT[24 * ZPAD + tid] = one;

  for (int c = 0; c < 10; ++c) {
    if (valid) {
      int ww = wc0 + dwb + c;
      float tw = fminf(fmaxf((ww + 0.5f) * SCALE - 0.5f, 0.f), 56.f);
      int j0 = min((int)tw, 55);
      float fw = tw - (float)j0;
      int rj = j0 - jb;
      if (rj != curj) {
        if (rj == curj + 1) {
          #pragma unroll
          for (int ch = 0; ch < 24; ++ch) u0[ch] = u1[ch];
        } else {
          LOADU(u0, rj)
        }
        LOADU(u1, rj + 1)
        curj = rj;
      }
      int m = lrow[ww] & (NMASK - 1);
      #pragma unroll
      for (int ch = 0; ch < 24; ++ch)
        zT[ch * ZPAD + tid] = f2bf(u0[ch] + fw * (u1[ch] - u0[ch]));
      It[prevm * IPAD + tid] = 0;
      It[m * IPAD + tid] = one;
      prevm = m;
    }
    __syncthreads();
    #pragma unroll
    for (int ks = 0; ks < 8; ++ks) {
      bf16x8 a  = *(bf16x8*)&It[(wv * 16 + l15) * IPAD + ks * 32 + khi];
      bf16x8 b0 = *(bf16x8*)&zT[l15 * ZPAD + ks * 32 + khi];
      bf16x8 b1 = *(bf16x8*)&zT[(16 + l15) * ZPAD + ks * 32 + khi];
      acc0 = __builtin_amdgcn_mfma_f32_16x16x32_bf16(a, b0, acc0, 0, 0, 0);
      acc1 = __builtin_amdgcn_mfma_f32_16x16x32_bf16(a, b1, acc1, 0, 0, 0);
    }
    __syncthreads();
  }
  #undef LOADU

  float* pb = part + ((size_t)b * NSLICE +
                      (size_t)(blockIdx.y * gridDim.x + blockIdx.x)) * (NMASK * PSTR);
  const int g4 = (lane >> 4) << 2;
  #pragma unroll
  for (int r = 0; r < 4; ++r) {
    int m = wv * 16 + g4 + r;
    pb[m * PSTR + l15] = acc0[r];
    if (l15 <= 8) pb[m * PSTR + 16 + l15] = acc1[r];
  }
}

// ---------- Kernel B2: meanFg[b][m][28] = sum(part)/cnt + b2 (pads 0) ----------
__global__ __launch_bounds__(256) void reduce_kernel(
    const float* __restrict__ part, const float* __restrict__ b2,
    float* __restrict__ meanFg)
{
  const int bm = blockIdx.x;          // b*64 + m
  const int b = bm >> 6, m = bm & 63;
  const int tid = threadIdx.x;        // = slice
  const float* p = part + ((size_t)b * NSLICE + tid) * (NMASK * PSTR) + (size_t)m * PSTR;
  float4 v[7];
  #pragma unroll
  for (int q = 0; q < 7; ++q) v[q] = *(const float4*)(p + q * 4);
  #pragma unroll
  for (int off = 32; off > 0; off >>= 1) {
    #pragma unroll
    for (int q = 0; q < 7; ++q) {
      v[q].x += __shfl_down(v[q].x, off, 64);
      v[q].y += __shfl_down(v[q].y, off, 64);
      v[q].z += __shfl_down(v[q].z, off, 64);
      v[q].w += __shfl_down(v[q].w, off, 64);
    }
  }
  __shared__ float s_red[4][28];
  const int wid = tid >> 6, lane = tid & 63;
  if (lane == 0) {
    #pragma unroll
    for (int q = 0; q < 7; ++q) *(float4*)&s_red[wid][q * 4] = v[q];
  }
  __syncthreads();
  if (tid < 28) {
    float cnt = s_red[0][24] + s_red[1][24] + s_red[2][24] + s_red[3][24];
    float t = s_red[0][tid] + s_red[1][tid] + s_red[2][tid] + s_red[3][tid];
    float out = (tid < L_OUT) ? t / fmaxf(cnt, 1.f) + b2[tid] : 0.f;
    meanFg[(size_t)bm * MFSTR + tid] = out;
  }
}

// ---------- Kernel C: out[b][l][hh][w] = lerp_w(rowC)[l] + meanF[label][l] ----------
__global__ __launch_bounds__(256) void final_kernel(
    const float* __restrict__ y57, const int* __restrict__ labels,
    const float* __restrict__ meanFg, float* __restrict__ out)
{
  __shared__ __align__(16) float rowC[FROWS][H_TOKN * RCSTR];
  __shared__ __align__(16) float meanF[NMASK * MFSTR];
  const int tid = threadIdx.x;
  const int hh0 = blockIdx.y * FROWS;
  const int b = blockIdx.z;
  const float* yb = y57 + (size_t)b * NPIX * YSTR;

  for (int i = tid; i < FROWS * H_TOKN * 6; i += 256) {
    int r = i / (H_TOKN * 6);
    int rest = i - r * (H_TOKN * 6);
    int rr = rest / 6, q = (rest - rr * 6) * 4;
    float th = fminf(fmaxf((hh0 + r + 0.5f) * SCALE - 0.5f, 0.f), 56.f);
    int i0 = min((int)th, 55);
    float fh = th - (float)i0;
    const float* s0 = yb + ((size_t)i0 * H_TOKN + rr) * YSTR + q;
    float4 A = *(const float4*)s0;
    float4 B = *(const float4*)(s0 + H_TOKN * YSTR);
    *(float4*)&rowC[r][rr * RCSTR + q] = make_float4(
        A.x + fh * (B.x - A.x), A.y + fh * (B.y - A.y),
        A.z + fh * (B.z - A.z), A.w + fh * (B.w - A.w));
  }
  {
    const float* src = meanFg + (size_t)b * NMASK * MFSTR;
    for (int i = tid; i < NMASK * MFSTR / 4; i += 256)
      *(float4*)&meanF[i * 4] = *(const float4*)(src + i * 4);
  }
  __syncthreads();

  for (int g = tid; g < FROWS * 200; g += 256) {
    const int row = g / 200;
    const int gg = g - row * 200;
    const int w0 = gg * 4;
    const int hh = hh0 + row;
    const int* lrow = labels + ((size_t)b * OUT_HW + hh) * OUT_HW;
    int4 la = *(const int4*)(lrow + w0);
    float* ob = out + (size_t)b * L_OUT * OUT_HW * OUT_HW + (size_t)hh * OUT_HW + w0;
    const float* rc = rowC[row];

    float fwv[4]; const float* c0p[4]; const float* mfp[4];
    {
      int lam[4] = {la.x & 63, la.y & 63, la.z & 63, la.w & 63};
      #pragma unroll
      for (int k = 0; k < 4; ++k) {
        float tw = fminf(fmaxf((w0 + k + 0.5f) * SCALE - 0.5f, 0.f), 56.f);
        int j0 = min((int)tw, 55);
        fwv[k] = tw - (float)j0;
        c0p[k] = &rc[j0 * RCSTR];
        mfp[k] = &meanF[lam[k] * MFSTR];
      }
    }
    #pragma unroll
    for (int q = 0; q < 6; ++q) {
      float4 V[4];
      #pragma unroll
      for (int k = 0; k < 4; ++k) {
        float4 A  = *(const float4*)(c0p[k] + 4 * q);
        float4 Bv = *(const float4*)(c0p[k] + RCSTR + 4 * q);
        float4 Mv = *(const float4*)(mfp[k] + 4 * q);
        V[k].x = A.x + fwv[k] * (Bv.x - A.x) + Mv.x;
        V[k].y = A.y + fwv[k] * (Bv.y - A.y) + Mv.y;
        V[k].z = A.z + fwv[k] * (Bv.z - A.z) + Mv.z;
        V[k].w = A.w + fwv[k] * (Bv.w - A.w) + Mv.w;
      }
      const int l = 4 * q;
      *(float4*)(ob + (size_t)l * 640000) = make_float4(V[0].x, V[1].x, V[2].x, V[3].x);
      if (l + 1 < L_OUT)
        *(float4*)(ob + (size_t)(l+1) * 640000) = make_float4(V[0].y, V[1].y, V[2].y, V[3].y);
      if (l + 2 < L_OUT)
        *(float4*)(ob + (size_t)(l+2) * 640000) = make_float4(V[0].z, V[1].z, V[2].z, V[3].z);
      if (l + 3 < L_OUT)
        *(float4*)(ob + (size_t)(l+3) * 640000) = make_float4(V[0].w, V[1].w, V[2].w, V[3].w);
    }
  }
}

extern "C" void kernel_launch(void* const* d_in, const int* in_sizes, int n_in,
                              void* d_out, int out_size, void* d_ws, size_t ws_size,
                              hipStream_t stream)
{
  const float* e   = (const float*)d_in[0];
  const int*   lab = (const int*)d_in[1];
  const float* w1  = (const float*)d_in[2];
  const float* b1  = (const float*)d_in[3];
  const float* w2  = (const float*)d_in[4];
  const float* b2  = (const float*)d_in[5];
  float* out = (float*)d_out;
  float* ws  = (float*)d_ws;

  float* y57_ws = ws;                                     // 6498*24 f32
  float* part   = y57_ws + (size_t)M_TOT * YSTR;          // 2*256*64*28 f32
  float* meanFg = part + (size_t)2 * NSLICE * NMASK * PSTR; // 2*64*28 f32

  fused_conv_kernel<<<dim3((M_TOT + BM - 1) / BM), NTHR, 0, stream>>>(
      e, w1, b1, w2, y57_ws);
  binsum_kernel<<<dim3(OUT_HW / TILE_W, OUT_HW / TILE_H, 2), 256, 0, stream>>>(
      lab, y57_ws, part);
  reduce_kernel<<<dim3(2 * NMASK), 256, 0, stream>>>(part, b2, meanFg);
  final_kernel<<<dim3(1, OUT_HW / FROWS, 2), 256, 0, stream>>>(
      y57_ws, lab, meanFg, out);
}